// Round 2
// baseline (737.735 us; speedup 1.0000x reference)
//
#include <hip/hip_runtime.h>

#define C_IN 10
#define C_OUT 64
#define BN_EPS 1e-3f
#define BP 128                 // pillars per bucket
#define MAX_NB 4704            // shared-mem histogram capacity

// ===========================================================================
// Fast path: counting-sort points by 128-pillar bucket, then per-bucket
// LDS max-pool. Zero global atomicMax; output written exactly once.
// ===========================================================================

__global__ __launch_bounds__(256) void zero_u32_kernel(unsigned* __restrict__ p, int n) {
    int i = blockIdx.x * 256 + threadIdx.x;
    int s = gridDim.x * 256;
    for (; i < n; i += s) p[i] = 0u;
}

// Phase A: per-bucket histogram (LDS-aggregated)
__global__ __launch_bounds__(256) void hist_kernel(const int* __restrict__ idx, int n,
                                                   unsigned* __restrict__ hist, int nb) {
    __shared__ unsigned h[MAX_NB];
    for (int i = threadIdx.x; i < nb; i += 256) h[i] = 0u;
    __syncthreads();
    int stride = gridDim.x * 256;
    for (int i = blockIdx.x * 256 + threadIdx.x; i < n; i += stride)
        atomicAdd(&h[((unsigned)idx[i]) >> 7], 1u);
    __syncthreads();
    for (int i = threadIdx.x; i < nb; i += 256) {
        unsigned v = h[i];
        if (v) atomicAdd(&hist[i], v);
    }
}

// Phase B: exclusive scan of hist -> cursor (single block)
__global__ __launch_bounds__(256) void scan_kernel(const unsigned* __restrict__ hist,
                                                   unsigned* __restrict__ cursor, int nb) {
    __shared__ unsigned partial[256];
    __shared__ unsigned base[256];
    int per = (nb + 255) / 256;
    int lo = threadIdx.x * per;
    int hi = lo + per; if (hi > nb) hi = nb;
    unsigned s = 0;
    for (int i = lo; i < hi; ++i) s += hist[i];
    partial[threadIdx.x] = s;
    __syncthreads();
    if (threadIdx.x == 0) {
        unsigned acc = 0;
        for (int t = 0; t < 256; ++t) { base[t] = acc; acc += partial[t]; }
    }
    __syncthreads();
    unsigned acc = base[threadIdx.x];
    for (int i = lo; i < hi; ++i) { cursor[i] = acc; acc += hist[i]; }
}

// Phase C: scatter packed records (localPillar<<22 | pointIdx) into bucket order.
// Afterwards cursor[b] == end offset of bucket b (start = cursor[b-1]).
__global__ __launch_bounds__(256) void scatter_ids_kernel(const int* __restrict__ idx, int n,
                                                          unsigned* __restrict__ cursor,
                                                          unsigned* __restrict__ rec) {
    int stride = gridDim.x * 256;
    for (int i = blockIdx.x * 256 + threadIdx.x; i < n; i += stride) {
        unsigned pid = (unsigned)idx[i];
        unsigned pos = atomicAdd(&cursor[pid >> 7], 1u);
        rec[pos] = ((pid & (BP - 1)) << 22) | (unsigned)i;
    }
}

// Phase D: per-bucket fused MLP + LDS max-pool + coalesced writeout.
// One wave per point-record; lane = output channel.
__global__ __launch_bounds__(256) void pool_kernel(
    const float* __restrict__ pts,
    const unsigned* __restrict__ rec,
    const unsigned* __restrict__ cursor,
    const float* __restrict__ W,
    const float* __restrict__ gamma,
    const float* __restrict__ beta,
    const float* __restrict__ mean,
    const float* __restrict__ var,
    float* __restrict__ out, int M)
{
    __shared__ unsigned smax[BP * C_OUT];   // 32 KB; bits of non-negative floats
    const int b    = blockIdx.x;
    const int lane = threadIdx.x & 63;
    const int wid  = threadIdx.x >> 6;

    for (int i = threadIdx.x; i < BP * C_OUT; i += 256) smax[i] = 0u;

    float w[C_IN];
#pragma unroll
    for (int j = 0; j < C_IN; ++j) w[j] = W[j * C_OUT + lane];
    const float scale = gamma[lane] * rsqrtf(var[lane] + BN_EPS);
    const float shift = fmaf(-mean[lane], scale, beta[lane]);

    const unsigned start = (b == 0) ? 0u : cursor[b - 1];
    const unsigned end   = cursor[b];
    __syncthreads();

    for (unsigned r = start + (unsigned)wid; r < end; r += 4) {
        const unsigned rc = rec[r];
        const unsigned p  = rc & 0x3FFFFFu;
        const unsigned lp = rc >> 22;
        const float* f = pts + (size_t)p * C_IN;   // wave-uniform row, HW broadcast
        float h = 0.f;
#pragma unroll
        for (int j = 0; j < C_IN; ++j) h = fmaf(f[j], w[j], h);
        h = fmaxf(fmaf(h, scale, shift), 0.f);     // BN + ReLU (>= 0)
        atomicMax(&smax[(lp << 6) + lane], __float_as_uint(h));
    }
    __syncthreads();

    // Writeout: 128x64 fp32 tile = 2048 float4, coalesced, non-atomic.
    const float4* s4 = (const float4*)smax;
    float4* o4 = (float4*)out;
    const size_t base4 = (size_t)b * (BP * C_OUT / 4);
    const size_t tot4  = (size_t)M * (C_OUT / 4);
    for (int i = threadIdx.x; i < BP * C_OUT / 4; i += 256) {
        size_t g = base4 + (size_t)i;
        if (g < tot4) o4[g] = s4[i];
    }
}

// ===========================================================================
// Fallback path (round-0 kernel): global atomicMax scatter.
// ===========================================================================
__global__ __launch_bounds__(256) void zero_out_kernel(float4* __restrict__ out4, int n4) {
    int i = blockIdx.x * blockDim.x + threadIdx.x;
    int stride = gridDim.x * blockDim.x;
    float4 z = make_float4(0.f, 0.f, 0.f, 0.f);
    for (int j = i; j < n4; j += stride) out4[j] = z;
}

__global__ __launch_bounds__(256) void pillar_scatter_kernel(
    const float* __restrict__ pts, const int* __restrict__ idx,
    const float* __restrict__ W, const float* __restrict__ gamma,
    const float* __restrict__ beta, const float* __restrict__ mean,
    const float* __restrict__ var, unsigned int* __restrict__ out, int npoints)
{
    const int lane = threadIdx.x & 63;
    float w[C_IN];
#pragma unroll
    for (int j = 0; j < C_IN; ++j) w[j] = W[j * C_OUT + lane];
    const float scale = gamma[lane] * rsqrtf(var[lane] + BN_EPS);
    const float shift = fmaf(-mean[lane], scale, beta[lane]);
    const int wave_id = (blockIdx.x * blockDim.x + threadIdx.x) >> 6;
    const int nwaves  = (gridDim.x * blockDim.x) >> 6;
    for (int p = wave_id; p < npoints; p += nwaves) {
        const float* f = pts + (size_t)p * C_IN;
        float h = 0.f;
#pragma unroll
        for (int j = 0; j < C_IN; ++j) h = fmaf(f[j], w[j], h);
        h = fmaxf(fmaf(h, scale, shift), 0.f);
        atomicMax(&out[(size_t)idx[p] * C_OUT + lane], __float_as_uint(h));
    }
}

// ===========================================================================

extern "C" void kernel_launch(void* const* d_in, const int* in_sizes, int n_in,
                              void* d_out, int out_size, void* d_ws, size_t ws_size,
                              hipStream_t stream) {
    const float* pts   = (const float*)d_in[0];
    const int*   idx   = (const int*)  d_in[1];
    const float* W     = (const float*)d_in[2];
    const float* gamma = (const float*)d_in[3];
    const float* beta  = (const float*)d_in[4];
    const float* mean  = (const float*)d_in[5];
    const float* var   = (const float*)d_in[6];

    const int npoints = in_sizes[0] / C_IN;     // 3,000,000
    const int M       = out_size / C_OUT;       // 600,000 pillars
    const int nb      = (M + BP - 1) / BP;      // 4688 buckets

    // workspace layout (u32): [0,nb) cursor | [nb,2nb) hist | [rec_off, +npoints) records
    const size_t rec_off    = ((size_t)(2 * nb) + 63) & ~(size_t)63;
    const size_t need_bytes = (rec_off + (size_t)npoints) * sizeof(unsigned);

    const bool fast = (nb <= MAX_NB) && (npoints < (1 << 22)) && (ws_size >= need_bytes);

    if (fast) {
        unsigned* cursor = (unsigned*)d_ws;
        unsigned* hist   = cursor + nb;
        unsigned* rec    = (unsigned*)d_ws + rec_off;

        zero_u32_kernel<<<(2 * nb + 255) / 256, 256, 0, stream>>>(cursor, 2 * nb);
        hist_kernel<<<256, 256, 0, stream>>>(idx, npoints, hist, nb);
        scan_kernel<<<1, 256, 0, stream>>>(hist, cursor, nb);
        scatter_ids_kernel<<<2048, 256, 0, stream>>>(idx, npoints, cursor, rec);
        pool_kernel<<<nb, 256, 0, stream>>>(pts, rec, cursor, W, gamma, beta, mean, var,
                                            (float*)d_out, M);
    } else {
        zero_out_kernel<<<2048, 256, 0, stream>>>((float4*)d_out, out_size / 4);
        pillar_scatter_kernel<<<2048, 256, 0, stream>>>(
            pts, idx, W, gamma, beta, mean, var, (unsigned int*)d_out, npoints);
    }
}

// Round 3
// 383.748 us; speedup vs baseline: 1.9224x; 1.9224x over previous
//
#include <hip/hip_runtime.h>

#define C_IN 10
#define C_OUT 64
#define BN_EPS 1e-3f
#define BP 128                 // pillars per bucket
#define MAX_NB 4704            // shared-mem histogram capacity
#define CHUNK 256              // points staged per block iteration
#define FSTRIDE 11             // feat LDS row stride (odd -> conflict-free)

// ===========================================================================
// Fast path: counting-sort points by 128-pillar bucket, then per-bucket
// LDS max-pool. Zero global atomicMax; output written exactly once.
// ===========================================================================

__global__ __launch_bounds__(256) void zero_u32_kernel(unsigned* __restrict__ p, int n) {
    int i = blockIdx.x * 256 + threadIdx.x;
    int s = gridDim.x * 256;
    for (; i < n; i += s) p[i] = 0u;
}

// Phase A: per-bucket histogram (LDS-aggregated)
__global__ __launch_bounds__(256) void hist_kernel(const int* __restrict__ idx, int n,
                                                   unsigned* __restrict__ hist, int nb) {
    __shared__ unsigned h[MAX_NB];
    for (int i = threadIdx.x; i < nb; i += 256) h[i] = 0u;
    __syncthreads();
    int stride = gridDim.x * 256;
    for (int i = blockIdx.x * 256 + threadIdx.x; i < n; i += stride)
        atomicAdd(&h[((unsigned)idx[i]) >> 7], 1u);
    __syncthreads();
    for (int i = threadIdx.x; i < nb; i += 256) {
        unsigned v = h[i];
        if (v) atomicAdd(&hist[i], v);
    }
}

// Phase B: exclusive scan of hist -> cursor (single block)
__global__ __launch_bounds__(256) void scan_kernel(const unsigned* __restrict__ hist,
                                                   unsigned* __restrict__ cursor, int nb) {
    __shared__ unsigned partial[256];
    __shared__ unsigned base[256];
    int per = (nb + 255) / 256;
    int lo = threadIdx.x * per;
    int hi = lo + per; if (hi > nb) hi = nb;
    unsigned s = 0;
    for (int i = lo; i < hi; ++i) s += hist[i];
    partial[threadIdx.x] = s;
    __syncthreads();
    if (threadIdx.x == 0) {
        unsigned acc = 0;
        for (int t = 0; t < 256; ++t) { base[t] = acc; acc += partial[t]; }
    }
    __syncthreads();
    unsigned acc = base[threadIdx.x];
    for (int i = lo; i < hi; ++i) { cursor[i] = acc; acc += hist[i]; }
}

// Phase C: scatter packed records (localPillar<<22 | pointIdx) into bucket order.
__global__ __launch_bounds__(256) void scatter_ids_kernel(const int* __restrict__ idx, int n,
                                                          unsigned* __restrict__ cursor,
                                                          unsigned* __restrict__ rec) {
    int stride = gridDim.x * 256;
    for (int i = blockIdx.x * 256 + threadIdx.x; i < n; i += stride) {
        unsigned pid = (unsigned)idx[i];
        unsigned pos = atomicAdd(&cursor[pid >> 7], 1u);
        rec[pos] = ((pid & (BP - 1)) << 22) | (unsigned)i;
    }
}

// Phase D: per-bucket fused MLP + LDS max-pool.
//   phase 1: lane=point  — coalesced rec read + parallel 5x float2 gather -> LDS
//   phase 2: lane=channel — LDS-broadcast compute + LDS atomicMax
//   register prefetch pipelines chunk n+1's gather under chunk n's compute.
__global__ __launch_bounds__(256) void pool_kernel(
    const float* __restrict__ pts,
    const unsigned* __restrict__ rec,
    const unsigned* __restrict__ cursor,
    const float* __restrict__ W,
    const float* __restrict__ gamma,
    const float* __restrict__ beta,
    const float* __restrict__ mean,
    const float* __restrict__ var,
    float* __restrict__ out, int M)
{
    __shared__ unsigned smax[BP * C_OUT];        // 32 KB (bits of non-neg floats)
    __shared__ float    feat[CHUNK * FSTRIDE];   // 11 KB, stride 11 => no bank conflicts
    __shared__ unsigned slp[CHUNK];              // 1 KB

    const int b    = blockIdx.x;
    const int t    = threadIdx.x;
    const int lane = t & 63;
    const int wid  = t >> 6;

    for (int i = t; i < BP * C_OUT; i += 256) smax[i] = 0u;

    float w[C_IN];
#pragma unroll
    for (int j = 0; j < C_IN; ++j) w[j] = W[j * C_OUT + lane];
    const float scale = gamma[lane] * rsqrtf(var[lane] + BN_EPS);
    const float shift = fmaf(-mean[lane], scale, beta[lane]);

    const unsigned start = (b == 0) ? 0u : cursor[b - 1];
    const int total = (int)(cursor[b] - start);

    // ---- register prefetch state (chunk currently staged in regs) ----
    float    fr[C_IN];
    unsigned rcr = 0;
    bool     hav = false;

    // prefetch chunk 0
    if (t < total) {
        rcr = rec[start + t];
        const float2* f2 = (const float2*)(pts + (size_t)(rcr & 0x3FFFFFu) * C_IN);
#pragma unroll
        for (int j = 0; j < 5; ++j) {
            float2 v = f2[j];
            fr[2 * j] = v.x; fr[2 * j + 1] = v.y;
        }
        hav = true;
    }

    for (int chunk = 0; chunk < total; chunk += CHUNK) {
        const int nrec = min(CHUNK, total - chunk);

        __syncthreads();                      // prev phase-2 done; smax init done
        if (hav) {                            // regs -> LDS
            slp[t] = rcr >> 22;
#pragma unroll
            for (int j = 0; j < C_IN; ++j) feat[t * FSTRIDE + j] = fr[j];
        }
        __syncthreads();

        // issue next chunk's gather now; latency hides under phase-2 compute
        const int nr = chunk + CHUNK + t;
        hav = false;
        if (nr < total) {
            rcr = rec[start + nr];
            const float2* f2 = (const float2*)(pts + (size_t)(rcr & 0x3FFFFFu) * C_IN);
#pragma unroll
            for (int j = 0; j < 5; ++j) {
                float2 v = f2[j];
                fr[2 * j] = v.x; fr[2 * j + 1] = v.y;
            }
            hav = true;
        }

        // phase 2: lane=channel, waves stride over staged points
        for (int i = wid; i < nrec; i += 4) {
            const unsigned lp = slp[i];
            const float* f = &feat[i * FSTRIDE];
            float h = 0.f;
#pragma unroll
            for (int j = 0; j < C_IN; ++j) h = fmaf(f[j], w[j], h);
            h = fmaxf(fmaf(h, scale, shift), 0.f);      // BN + ReLU (>= 0)
            atomicMax(&smax[(lp << 6) + lane], __float_as_uint(h));
        }
    }
    __syncthreads();

    // Writeout: 128x64 fp32 tile = 2048 float4, coalesced, non-atomic.
    const float4* s4 = (const float4*)smax;
    float4* o4 = (float4*)out;
    const size_t base4 = (size_t)b * (BP * C_OUT / 4);
    const size_t tot4  = (size_t)M * (C_OUT / 4);
    for (int i = t; i < BP * C_OUT / 4; i += 256) {
        size_t g = base4 + (size_t)i;
        if (g < tot4) o4[g] = s4[i];
    }
}

// ===========================================================================
// Fallback path (round-0 kernel): global atomicMax scatter.
// ===========================================================================
__global__ __launch_bounds__(256) void zero_out_kernel(float4* __restrict__ out4, int n4) {
    int i = blockIdx.x * blockDim.x + threadIdx.x;
    int stride = gridDim.x * blockDim.x;
    float4 z = make_float4(0.f, 0.f, 0.f, 0.f);
    for (int j = i; j < n4; j += stride) out4[j] = z;
}

__global__ __launch_bounds__(256) void pillar_scatter_kernel(
    const float* __restrict__ pts, const int* __restrict__ idx,
    const float* __restrict__ W, const float* __restrict__ gamma,
    const float* __restrict__ beta, const float* __restrict__ mean,
    const float* __restrict__ var, unsigned int* __restrict__ out, int npoints)
{
    const int lane = threadIdx.x & 63;
    float w[C_IN];
#pragma unroll
    for (int j = 0; j < C_IN; ++j) w[j] = W[j * C_OUT + lane];
    const float scale = gamma[lane] * rsqrtf(var[lane] + BN_EPS);
    const float shift = fmaf(-mean[lane], scale, beta[lane]);
    const int wave_id = (blockIdx.x * blockDim.x + threadIdx.x) >> 6;
    const int nwaves  = (gridDim.x * blockDim.x) >> 6;
    for (int p = wave_id; p < npoints; p += nwaves) {
        const float* f = pts + (size_t)p * C_IN;
        float h = 0.f;
#pragma unroll
        for (int j = 0; j < C_IN; ++j) h = fmaf(f[j], w[j], h);
        h = fmaxf(fmaf(h, scale, shift), 0.f);
        atomicMax(&out[(size_t)idx[p] * C_OUT + lane], __float_as_uint(h));
    }
}

// ===========================================================================

extern "C" void kernel_launch(void* const* d_in, const int* in_sizes, int n_in,
                              void* d_out, int out_size, void* d_ws, size_t ws_size,
                              hipStream_t stream) {
    const float* pts   = (const float*)d_in[0];
    const int*   idx   = (const int*)  d_in[1];
    const float* W     = (const float*)d_in[2];
    const float* gamma = (const float*)d_in[3];
    const float* beta  = (const float*)d_in[4];
    const float* mean  = (const float*)d_in[5];
    const float* var   = (const float*)d_in[6];

    const int npoints = in_sizes[0] / C_IN;     // 3,000,000
    const int M       = out_size / C_OUT;       // 600,000 pillars
    const int nb      = (M + BP - 1) / BP;      // 4688 buckets

    // workspace layout (u32): [0,nb) cursor | [nb,2nb) hist | [rec_off, +npoints) records
    const size_t rec_off    = ((size_t)(2 * nb) + 63) & ~(size_t)63;
    const size_t need_bytes = (rec_off + (size_t)npoints) * sizeof(unsigned);

    const bool fast = (nb <= MAX_NB) && (npoints < (1 << 22)) && (ws_size >= need_bytes);

    if (fast) {
        unsigned* cursor = (unsigned*)d_ws;
        unsigned* hist   = cursor + nb;
        unsigned* rec    = (unsigned*)d_ws + rec_off;

        zero_u32_kernel<<<(2 * nb + 255) / 256, 256, 0, stream>>>(cursor, 2 * nb);
        hist_kernel<<<256, 256, 0, stream>>>(idx, npoints, hist, nb);
        scan_kernel<<<1, 256, 0, stream>>>(hist, cursor, nb);
        scatter_ids_kernel<<<2048, 256, 0, stream>>>(idx, npoints, cursor, rec);
        pool_kernel<<<nb, 256, 0, stream>>>(pts, rec, cursor, W, gamma, beta, mean, var,
                                            (float*)d_out, M);
    } else {
        zero_out_kernel<<<2048, 256, 0, stream>>>((float4*)d_out, out_size / 4);
        pillar_scatter_kernel<<<2048, 256, 0, stream>>>(
            pts, idx, W, gamma, beta, mean, var, (unsigned int*)d_out, npoints);
    }
}